// Round 3
// baseline (2130.594 us; speedup 1.0000x reference)
//
#include <hip/hip_runtime.h>
#include <hip/hip_bf16.h>
#include <stdint.h>
#include <math.h>

#define DEV __device__ __forceinline__

typedef __hip_bfloat16 bf16;
typedef __attribute__((ext_vector_type(8))) __bf16 bf16x8;
typedef __attribute__((ext_vector_type(8))) unsigned short u16x8;
typedef __attribute__((ext_vector_type(4))) float f32x4;

static constexpr int B_ = 2;
static constexpr int T_ = 4096;
static constexpr int C_ = 2048;
static constexpr int H_ = 32;

// ---------- helpers ----------
DEV void gld_lds16(const void* g, void* l) {
  __builtin_amdgcn_global_load_lds((const __attribute__((address_space(1))) void*)g,
                                   (__attribute__((address_space(3))) void*)l, 16, 0, 0);
}
DEV void gld_lds4(const void* g, void* l) {
  __builtin_amdgcn_global_load_lds((const __attribute__((address_space(1))) void*)g,
                                   (__attribute__((address_space(3))) void*)l, 4, 0, 0);
}
DEV float bfbits2f(unsigned short u) {
  unsigned int x = ((unsigned int)u) << 16;
  return __builtin_bit_cast(float, x);
}
DEV unsigned short f2bfbits(float f) { bf16 h = __float2bfloat16(f); return __builtin_bit_cast(unsigned short, h); }
DEV void store_bf16x4(bf16* p, f32x4 v) {
  ushort4 u;
  u.x = f2bfbits(v.x); u.y = f2bfbits(v.y); u.z = f2bfbits(v.z); u.w = f2bfbits(v.w);
  *reinterpret_cast<ushort4*>(p) = u;
}
DEV float wsum64(float v) {
#pragma unroll
  for (int m = 32; m > 0; m >>= 1) v += __shfl_xor(v, m, 64);
  return v;
}
template<int CTRL>
DEV float dpp_add(float v) {
  int x = __builtin_bit_cast(int, v);
  int y = __builtin_amdgcn_update_dpp(0, x, CTRL, 0xf, 0xf, false);
  return v + __builtin_bit_cast(float, y);
}
// sum across the 8 lanes whose lane-bits {0,1,3} vary (bits 2,4,5 fixed)
DEV float red8(float v) {
  v = dpp_add<0xB1>(v);    // quad_perm xor1
  v = dpp_add<0x4E>(v);    // quad_perm xor2
  v = dpp_add<0x128>(v);   // row_ror:8 == xor8 within row-16
  return v;
}

// ---------- GEMM: C[m][n] = sum_k A[m][k]*B[n][k], bf16 in, f32 accum ----------
// 128x128 tile, BK=64, 4 waves (2x2), 16x16x32 MFMA, global_load_lds width-16.
// MODE: 0 f32 [M][N]; 2 bf16 flat; 3 bf16 tanh; 4 bf16 sigmoid;
//       7 bf16 transposed [B,H,T,64]; 8 bf16 transposed wdec(ep+val);
//       9 bf16 transposed sigmoid(ep+val)
template<int MODE>
__global__ __launch_bounds__(256)
void gemm_bt(const bf16* __restrict__ A, const bf16* __restrict__ Bm,
             void* __restrict__ Cout, const float* __restrict__ ep,
             int N, int K, int T4)
{
  __shared__ bf16 lA[128 * 64];
  __shared__ bf16 lB[128 * 64];
  const int tid  = threadIdx.x;
  const int wave = tid >> 6;
  const int lane = tid & 63;
  const long brow = (long)blockIdx.x * 128;
  const long bcol = (long)blockIdx.y * 128;
  const int wr = wave >> 1, wc = wave & 1;

  f32x4 acc[4][4];
#pragma unroll
  for (int m = 0; m < 4; ++m)
#pragma unroll
    for (int n = 0; n < 4; ++n)
      acc[m][n] = f32x4{0.f, 0.f, 0.f, 0.f};

  const bf16* pa = A  + (size_t)(brow + wave * 32 + (lane >> 3)) * K + (lane & 7) * 8;
  const bf16* pb = Bm + (size_t)(bcol + wave * 32 + (lane >> 3)) * K + (lane & 7) * 8;

  for (int k0 = 0; k0 < K; k0 += 64) {
#pragma unroll
    for (int i = 0; i < 4; ++i) gld_lds16(pa + (size_t)i * 8 * K, &lA[(wave * 4 + i) * 512]);
#pragma unroll
    for (int i = 0; i < 4; ++i) gld_lds16(pb + (size_t)i * 8 * K, &lB[(wave * 4 + i) * 512]);
    pa += 64; pb += 64;
    __syncthreads();
#pragma unroll
    for (int kk = 0; kk < 2; ++kk) {
      bf16x8 af[4], bfv[4];
#pragma unroll
      for (int m = 0; m < 4; ++m)
        af[m] = *(const bf16x8*)&lA[(wr * 64 + m * 16 + (lane & 15)) * 64 + kk * 32 + (lane >> 4) * 8];
#pragma unroll
      for (int n = 0; n < 4; ++n)
        bfv[n] = *(const bf16x8*)&lB[(wc * 64 + n * 16 + (lane & 15)) * 64 + kk * 32 + (lane >> 4) * 8];
#pragma unroll
      for (int m = 0; m < 4; ++m)
#pragma unroll
        for (int n = 0; n < 4; ++n)
          acc[m][n] = __builtin_amdgcn_mfma_f32_16x16x32_bf16(af[m], bfv[n], acc[m][n], 0, 0, 0);
    }
    __syncthreads();
  }

  const int cr = (lane >> 4) * 4;
  const int cc = lane & 15;
#pragma unroll
  for (int m = 0; m < 4; ++m) {
#pragma unroll
    for (int n = 0; n < 4; ++n) {
#pragma unroll
      for (int j = 0; j < 4; ++j) {
        long gm = brow + wr * 64 + m * 16 + cr + j;
        long gn = bcol + wc * 64 + n * 16 + cc;
        float val = acc[m][n][j];
        if constexpr (MODE == 0) {
          ((float*)Cout)[gm * N + gn] = val;
        } else if constexpr (MODE == 2) {
          ((bf16*)Cout)[gm * N + gn] = __float2bfloat16(val);
        } else if constexpr (MODE == 3) {
          ((bf16*)Cout)[gm * N + gn] = __float2bfloat16(tanhf(val));
        } else if constexpr (MODE == 4) {
          ((bf16*)Cout)[gm * N + gn] = __float2bfloat16(1.f / (1.f + expf(-val)));
        } else if constexpr (MODE == 7) {
          long b = gm / T4, t = gm % T4;
          ((bf16*)Cout)[((b * (N >> 6) + (gn >> 6)) * T4 + t) * 64 + (gn & 63)] = __float2bfloat16(val);
        } else if constexpr (MODE == 8) {
          float u = ep[gn] + val;                 // w0 + lora
          float w = -log1pf(expf(-u)) - 0.5f;     // -softplus(-u) - 0.5
          float wd = expf(-expf(w));
          long b = gm / T4, t = gm % T4;
          ((bf16*)Cout)[((b * (N >> 6) + (gn >> 6)) * T4 + t) * 64 + (gn & 63)] = __float2bfloat16(wd);
        } else if constexpr (MODE == 9) {
          float sg = 1.f / (1.f + expf(-(ep[gn] + val)));
          long b = gm / T4, t = gm % T4;
          ((bf16*)Cout)[((b * (N >> 6) + (gn >> 6)) * T4 + t) * 64 + (gn & 63)] = __float2bfloat16(sg);
        }
      }
    }
  }
}

// ---------- single token-shift mix ----------
__global__ __launch_bounds__(256)
void mix1(const float* __restrict__ x, const float* __restrict__ coef,
          bf16* __restrict__ out)
{
  size_t e = ((size_t)blockIdx.x * 256 + threadIdx.x) * 4;
  int c = (int)(e & (C_ - 1));
  size_t m = e >> 11;
  f32x4 xc = *(const f32x4*)(x + e);
  f32x4 xp;
  if ((m & (T_ - 1)) == 0) xp = f32x4{0.f, 0.f, 0.f, 0.f};
  else                     xp = *(const f32x4*)(x + e - C_);
  f32x4 cf = *(const f32x4*)(coef + c);
  store_bf16x4(out + e, xc + (xp - xc) * cf);
}

// ---------- f32 -> bf16 weight convert (4M elems) ----------
__global__ __launch_bounds__(256)
void cvt1(const float* __restrict__ s, bf16* __restrict__ d)
{
  size_t e = ((size_t)blockIdx.x * 256 + threadIdx.x) * 4;
  store_bf16x4(d + e, *(const f32x4*)(s + e));
}

// ---------- transpose+pad LoRA weights to [NP][RP] bf16, dst[n][r]=src[r][n] ----------
struct TPJob { const float* s; bf16* d; int R, Cs, NP, RP; };
struct TP8 { TPJob j[8]; };
__global__ __launch_bounds__(256)
void tpad(TP8 jobs)
{
  TPJob J = jobs.j[blockIdx.y];
  int i = blockIdx.x * 256 + threadIdx.x;
  int tot = J.NP * J.RP;
  if (i >= tot) return;
  int n = i / J.RP, r = i - n * J.RP;
  float v = (n < J.Cs && r < J.R) ? J.s[(size_t)r * J.Cs + n] : 0.f;
  J.d[i] = __float2bfloat16(v);
}

// ---------- prescan: kk-norm, k-adjust, v-mix, bonus scalar; in-place b/kkn ----------
__global__ __launch_bounds__(256)
void prescan2(const bf16* __restrict__ r16, bf16* __restrict__ k16,
              bf16* __restrict__ v16, bf16* __restrict__ ab,      // a_sig_t -> b16
              bf16* __restrict__ vn16,                            // v_sig_t -> kkn16
              const float* __restrict__ vfirst, const float* __restrict__ kkc,
              const float* __restrict__ kac, const float* __restrict__ rk,
              float* __restrict__ sbonus)
{
  const int wid = threadIdx.x >> 6;
  const int lane = threadIdx.x & 63;
  const long id = (long)blockIdx.x * 4 + wid;   // bh*T + t
  const long bh = id >> 12;
  const long t = id & (T_ - 1);
  const long b = bh >> 5, h = bh & (H_ - 1);
  const long mrow = b * T_ + t;
  const int c = (int)(h * 64 + lane);
  const size_t tp = (size_t)id * 64 + lane;
  float k  = __bfloat162float(k16[tp]);
  float v  = __bfloat162float(v16[tp]);
  float r  = __bfloat162float(r16[tp]);
  float a  = __bfloat162float(ab[tp]);
  float vs = __bfloat162float(vn16[tp]);
  float vf = vfirst[mrow * C_ + c];
  float kkv = k * kkc[c];
  float ssum = wsum64(kkv * kkv);
  float kkn = kkv / fmaxf(sqrtf(ssum), 1e-12f);
  float kn = k * (1.f + (a - 1.f) * kac[c]);
  float vn = v + (vf - v) * vs;
  k16[tp] = __float2bfloat16(kn);
  v16[tp] = __float2bfloat16(vn);
  ab[tp]  = __float2bfloat16(kkn * a);   // b = kk * a
  vn16[tp] = __float2bfloat16(kkn);      // scan negates for a_t = -kk
  float bs = wsum64(r * kn * rk[c]);     // bonus scalar per (b,h,t)
  if (lane == 0) sbonus[id] = bs;
}

// ---------- WKV7 sequential scan ----------
// 512 blocks = 8 v-groups x 64 (b,h); one wave each. blockIdx ≡ bh (mod 64) so all
// 8 v-groups of a head share an XCD (L2 reuse of the 6 streams).
// lane bits {0,1,3} = q (k-octet), bits {2,4,5} = vl; S[8] = rows g*8+vl, cols q*8..+8.
// bf16 streams staged 2 steps at a time via global_load_lds into a 4-slot ring;
// depth-3 prefetch, hand-counted s_waitcnt vmcnt(12) (exact at prologue bound).
__global__ __launch_bounds__(64)
void wkv_scan3(const bf16* __restrict__ r16, const bf16* __restrict__ w16,
               const bf16* __restrict__ k16, const bf16* __restrict__ v16,
               const bf16* __restrict__ n16, const bf16* __restrict__ b16,
               bf16* __restrict__ y16)
{
  __shared__ __align__(16) char ring[4][1536];
  const int bh = blockIdx.x & 63;
  const int g = blockIdx.x >> 6;
  const int lane = threadIdx.x;
  const int q  = (lane & 3) | ((lane & 8) >> 1);
  const int vl = ((lane >> 2) & 1) | ((lane >> 3) & 6);
  const int vrow = g * 8 + vl;
  const size_t eb = (size_t)bh * (T_ * 64);
  const bf16* ps[6] = { r16 + eb, w16 + eb, k16 + eb, v16 + eb, n16 + eb, b16 + eb };

  auto stage = [&](int ss, int slot) {
    char* d = &ring[slot][0];
#pragma unroll
    for (int j = 0; j < 6; ++j)
      gld_lds4(ps[j] + (size_t)ss * 128 + lane * 2, d + j * 256);
  };
  stage(0, 0); stage(1, 1); stage(2, 2);

  float S[8];
#pragma unroll
  for (int j = 0; j < 8; ++j) S[j] = 0.f;

  const int NS = T_ / 2;
  for (int ss = 0; ss < NS; ++ss) {
    // 6 loads + 2 stores per superstep, depth-3 prefetch: >=12 newer VM events
    // always separate slot-ss's loads from this wait (exactly 12 at ss=0).
    asm volatile("s_waitcnt vmcnt(12)" ::: "memory");
    int nx = ss + 3; if (nx >= NS) nx = NS - 1;   // clamped tail keeps counts uniform
    stage(nx, (ss + 3) & 3);
    const char* sp = &ring[ss & 3][0];
#pragma unroll
    for (int st = 0; st < 2; ++st) {
      u16x8 Ru = *(const u16x8*)(sp + 0    + st * 128 + q * 16);
      u16x8 Wu = *(const u16x8*)(sp + 256  + st * 128 + q * 16);
      u16x8 Ku = *(const u16x8*)(sp + 512  + st * 128 + q * 16);
      u16x8 Nu = *(const u16x8*)(sp + 1024 + st * 128 + q * 16);
      u16x8 Bu = *(const u16x8*)(sp + 1280 + st * 128 + q * 16);
      float vt = bfbits2f(*(const unsigned short*)(sp + 768 + st * 128 + vrow * 2));
      float sa = 0.f;
#pragma unroll
      for (int j = 0; j < 8; ++j) sa = fmaf(S[j], bfbits2f(Nu[j]), sa);
      sa = red8(sa);
      float nsa = -sa;                       // a_t = -kk
      float yp = 0.f;
#pragma unroll
      for (int j = 0; j < 8; ++j) {
        S[j] = fmaf(vt, bfbits2f(Ku[j]), fmaf(nsa, bfbits2f(Bu[j]), S[j] * bfbits2f(Wu[j])));
        yp = fmaf(S[j], bfbits2f(Ru[j]), yp);
      }
      yp = red8(yp);
      if (q == 0) y16[eb + (size_t)(2 * ss + st) * 64 + vrow] = __float2bfloat16(yp);
    }
  }
}

// ---------- post: GroupNorm + bonus + gate -> bf16 A for output GEMM ----------
__global__ __launch_bounds__(256)
void postk2(const bf16* __restrict__ y16, const bf16* __restrict__ v16,
            const float* __restrict__ sbonus, const bf16* __restrict__ g16,
            const float* __restrict__ lnw, const float* __restrict__ lnb,
            bf16* __restrict__ opre)
{
  const int wid = threadIdx.x >> 6;
  const int lane = threadIdx.x & 63;
  const long id = (long)blockIdx.x * 4 + wid;
  const long bh = id >> 12;
  const long t = id & (T_ - 1);
  const long b = bh >> 5, h = bh & (H_ - 1);
  const long mrow = b * T_ + t;
  const int c = (int)(h * 64 + lane);
  const size_t tp = (size_t)id * 64 + lane;
  float y = __bfloat162float(y16[tp]);
  float mu = wsum64(y) * (1.f / 64.f);
  float d = y - mu;
  float var = wsum64(d * d) * (1.f / 64.f);
  float yn = d * rsqrtf(var + 0.00064f) * lnw[c] + lnb[c];
  float outv = (yn + sbonus[id] * __bfloat162float(v16[tp]))
               * __bfloat162float(g16[mrow * C_ + c]);
  opre[mrow * C_ + c] = __float2bfloat16(outv);
}

// ---------- launch ----------
extern "C" void kernel_launch(void* const* d_in, const int* in_sizes, int n_in,
                              void* d_out, int out_size, void* d_ws, size_t ws_size,
                              hipStream_t stream)
{
  const float* x    = (const float*)d_in[0];
  const float* vfst = (const float*)d_in[1];
  const float* x_r  = (const float*)d_in[2];
  const float* x_w  = (const float*)d_in[3];
  const float* x_k  = (const float*)d_in[4];
  const float* x_v  = (const float*)d_in[5];
  const float* x_a  = (const float*)d_in[6];
  const float* x_g  = (const float*)d_in[7];
  const float* w0   = (const float*)d_in[8];
  const float* w1   = (const float*)d_in[9];
  const float* w2   = (const float*)d_in[10];
  const float* a0   = (const float*)d_in[11];
  const float* a1   = (const float*)d_in[12];
  const float* a2   = (const float*)d_in[13];
  const float* v0   = (const float*)d_in[14];
  const float* v1   = (const float*)d_in[15];
  const float* v2   = (const float*)d_in[16];
  const float* g1   = (const float*)d_in[17];
  const float* g2   = (const float*)d_in[18];
  const float* k_k  = (const float*)d_in[19];
  const float* k_a  = (const float*)d_in[20];
  const float* r_k  = (const float*)d_in[21];
  const float* W_r  = (const float*)d_in[22];
  const float* W_k  = (const float*)d_in[23];
  const float* W_v  = (const float*)d_in[24];
  const float* W_o  = (const float*)d_in[25];
  const float* lnw  = (const float*)d_in[26];
  const float* lnb  = (const float*)d_in[27];

  const size_t MB = 1048576ULL;
  const size_t HK = 524288ULL;
  // DIAGNOSTIC GUARD: if ws is too small, skip all work -> absmax-fail WITHOUT a
  // crash tells us ws_size < 248MB; a crash means the bug is elsewhere.
  if (ws_size < 248 * MB) return;

  char* ws = (char*)d_ws;
  bf16* r16    = (bf16*)(ws + 0 * MB);     // [B,H,T,64]
  bf16* k16    = (bf16*)(ws + 32 * MB);
  bf16* v16    = (bf16*)(ws + 64 * MB);
  bf16* wdec16 = (bf16*)(ws + 96 * MB);    // dead after scan -> opre
  bf16* opre   = (bf16*)(ws + 96 * MB);
  bf16* asig   = (bf16*)(ws + 128 * MB);   // a_sig_t -> b16 in-place at prescan
  bf16* vsig   = (bf16*)(ws + 160 * MB);   // v_sig_t -> kkn16 in-place
  bf16* w1t = (bf16*)(ws + 192 * MB);
  bf16* a1t = (bf16*)(ws + 192 * MB + HK);
  bf16* v1t = (bf16*)(ws + 193 * MB);
  bf16* g1t = (bf16*)(ws + 193 * MB + HK); // 1MB
  bf16* w2t = (bf16*)(ws + 194 * MB + HK);
  bf16* a2t = (bf16*)(ws + 195 * MB);
  bf16* v2t = (bf16*)(ws + 195 * MB + HK);
  bf16* g2t = (bf16*)(ws + 196 * MB);      // 1MB -> ends 197MB
  bf16* WB  = (bf16*)(ws + 197 * MB);      // 8MB sequential weight-cvt buffer
  bf16* h_w = (bf16*)(ws + 205 * MB);      // [8192][128] 2MB
  bf16* h_a = (bf16*)(ws + 207 * MB);
  bf16* h_v = (bf16*)(ws + 209 * MB);
  bf16* h_g = (bf16*)(ws + 211 * MB);      // [8192][256] 4MB
  float* sb = (float*)(ws + 215 * MB);     // bonus scalars [B,H,T] 1MB
  bf16* y16 = (bf16*)(ws + 216 * MB);      // scan out, ends 248MB
  bf16* g16 = (bf16*)d_out;                // gate bf16 parks in d_out lower half
  bf16* MIX = (bf16*)((char*)d_out + 32 * MB); // recycled mix buffer, upper half

  TP8 jobs;
  jobs.j[0] = TPJob{ w1, w1t, 2048,   96,  128, 2048 };
  jobs.j[1] = TPJob{ a1, a1t, 2048,   96,  128, 2048 };
  jobs.j[2] = TPJob{ v1, v1t, 2048,   64,  128, 2048 };
  jobs.j[3] = TPJob{ g1, g1t, 2048,  256,  256, 2048 };
  jobs.j[4] = TPJob{ w2, w2t,   96, 2048, 2048,  128 };
  jobs.j[5] = TPJob{ a2, a2t,   96, 2048, 2048,  128 };
  jobs.j[6] = TPJob{ v2, v2t,   64, 2048, 2048,  128 };
  jobs.j[7] = TPJob{ g2, g2t,  256, 2048, 2048,  256 };
  tpad<<<dim3(2048, 8), 256, 0, stream>>>(jobs);

  // LoRA stage-1 (mix recomputed per GEMM; activation fused)
  mix1<<<dim3(16384), 256, 0, stream>>>(x, x_w, MIX);
  gemm_bt<3><<<dim3(64, 1), 256, 0, stream>>>(MIX, w1t, h_w, nullptr, 128, 2048, 0);
  mix1<<<dim3(16384), 256, 0, stream>>>(x, x_a, MIX);
  gemm_bt<2><<<dim3(64, 1), 256, 0, stream>>>(MIX, a1t, h_a, nullptr, 128, 2048, 0);
  mix1<<<dim3(16384), 256, 0, stream>>>(x, x_v, MIX);
  gemm_bt<2><<<dim3(64, 1), 256, 0, stream>>>(MIX, v1t, h_v, nullptr, 128, 2048, 0);
  mix1<<<dim3(16384), 256, 0, stream>>>(x, x_g, MIX);
  gemm_bt<4><<<dim3(64, 2), 256, 0, stream>>>(MIX, g1t, h_g, nullptr, 256, 2048, 0);

  // LoRA stage-2 (wdec / sigmoids fused, head-transposed outputs; gate -> d_out)
  gemm_bt<8><<<dim3(64, 16), 256, 0, stream>>>(h_w, w2t, wdec16, w0, 2048, 128, T_);
  gemm_bt<9><<<dim3(64, 16), 256, 0, stream>>>(h_a, a2t, asig, a0, 2048, 128, T_);
  gemm_bt<9><<<dim3(64, 16), 256, 0, stream>>>(h_v, v2t, vsig, v0, 2048, 128, T_);
  gemm_bt<2><<<dim3(64, 16), 256, 0, stream>>>(h_g, g2t, g16, nullptr, 2048, 256, 0);

  // big projections (weight cvt + mix recycled buffers) -> bf16 [B,H,T,64]
  cvt1<<<dim3(4096), 256, 0, stream>>>(W_r, WB);
  mix1<<<dim3(16384), 256, 0, stream>>>(x, x_r, MIX);
  gemm_bt<7><<<dim3(64, 16), 256, 0, stream>>>(MIX, WB, r16, nullptr, 2048, 2048, T_);
  cvt1<<<dim3(4096), 256, 0, stream>>>(W_k, WB);
  mix1<<<dim3(16384), 256, 0, stream>>>(x, x_k, MIX);
  gemm_bt<7><<<dim3(64, 16), 256, 0, stream>>>(MIX, WB, k16, nullptr, 2048, 2048, T_);
  cvt1<<<dim3(4096), 256, 0, stream>>>(W_v, WB);
  mix1<<<dim3(16384), 256, 0, stream>>>(x, x_v, MIX);
  gemm_bt<7><<<dim3(64, 16), 256, 0, stream>>>(MIX, WB, v16, nullptr, 2048, 2048, T_);

  prescan2<<<dim3(65536), 256, 0, stream>>>(r16, k16, v16, asig, vsig,
                                            vfst, k_k, k_a, r_k, sb);
  wkv_scan3<<<dim3(512), 64, 0, stream>>>(r16, wdec16, k16, v16, vsig, asig, y16);
  postk2<<<dim3(65536), 256, 0, stream>>>(y16, v16, sb, g16, lnw, lnb, opre);

  cvt1<<<dim3(4096), 256, 0, stream>>>(W_o, WB);
  gemm_bt<0><<<dim3(64, 16), 256, 0, stream>>>(opre, WB, (float*)d_out, nullptr, 2048, 2048, 0);
}